// Round 9
// baseline (1135.635 us; speedup 1.0000x reference)
//
#include <hip/hip_runtime.h>
#include <hip/hip_cooperative_groups.h>
#include <hip/hip_bf16.h>
#include <math.h>

namespace cg = cooperative_groups;

// Problem dims
#define SDIM 256
#define HDIM 768
#define EDIM 1536
#define NDIM 16
#define KCONV 4
#define RDIM 48
#define NLAYER 2
#define LSEQ 1024

#define NCHUNK 64
#define CHLEN (LSEQ / NCHUNK)   // 16
#define KSPLIT 8
#define KCH (EDIM / KSPLIT)     // 192

typedef __hip_bfloat16 bf16;
typedef __attribute__((ext_vector_type(8))) short short8;
typedef __attribute__((ext_vector_type(4))) float f32x4;

__device__ __forceinline__ float softplusf(float x) {
    return (x > 20.f) ? x : log1pf(expf(x));
}
__device__ __forceinline__ float siluf(float x) {
    return x / (1.f + expf(-x));
}

struct MegaArgs {
    const float *x, *emb_w, *emb_b, *norm_w, *in_proj, *conv_w, *conv_b, *x_proj;
    const float *dt_w, *dt_b, *A_log, *Dp, *out_proj, *head_w, *head_b;
    float *out;
    float *h, *res, *xz, *u, *dbc, *part, *dtb, *chunkS, *sumdt, *sInit;
    bf16 *hnb, *yzb, *hb, *xb, *emb_wb, *head_wb, *in_wb, *out_wb;
};

// ======== shared stage bodies (gridDim.x-stride; used by mega AND fallback) ========

__device__ __forceinline__ void f2b_seg(const float* __restrict__ in,
                                        bf16* __restrict__ out, int n)
{
    for (int i = (blockIdx.x * 256 + threadIdx.x) * 4; i < n; i += gridDim.x * 256 * 4) {
        float4 v = *(const float4*)(in + i);
        out[i + 0] = (bf16)v.x; out[i + 1] = (bf16)v.y;
        out[i + 2] = (bf16)v.z; out[i + 3] = (bf16)v.w;
    }
}

// bf16 MFMA 64x64 tile: out[1024,N] = A[1024,K] @ W[N,K]^T
__device__ __forceinline__ void gemm_tile(
    const bf16* __restrict__ A, int lda, const bf16* __restrict__ W, int ldw,
    const float* __restrict__ bias, float* __restrict__ out, bf16* __restrict__ outb,
    int N, int Kd, int bx, int by,
    short (*As)[72], short (*Ws)[72], bool useBias, bool useOutb)
{
    const int tid  = threadIdx.x;
    const int lane = tid & 63, wid = tid >> 6;
    const int wm = wid >> 1, wn = wid & 1;
    const int row0 = by * 64, col0 = bx * 64;
    const int quad = lane >> 4, l16 = lane & 15;

    f32x4 acc[2][2] = {};
    for (int k0 = 0; k0 < Kd; k0 += 64) {
        #pragma unroll
        for (int i = 0; i < 2; i++) {
            int id = tid + i * 256;
            int r = id >> 3, g = id & 7;
            *(uint4*)&As[r][g * 8] = *(const uint4*)(A + (size_t)(row0 + r) * lda + k0 + g * 8);
            *(uint4*)&Ws[r][g * 8] = *(const uint4*)(W + (size_t)(col0 + r) * ldw + k0 + g * 8);
        }
        __syncthreads();
        #pragma unroll
        for (int ks = 0; ks < 64; ks += 32) {
            short8 af[2], bfr[2];
            #pragma unroll
            for (int i = 0; i < 2; i++) af[i] = *(const short8*)&As[wm * 32 + i * 16 + l16][ks + quad * 8];
            #pragma unroll
            for (int j = 0; j < 2; j++) bfr[j] = *(const short8*)&Ws[wn * 32 + j * 16 + l16][ks + quad * 8];
            #pragma unroll
            for (int i = 0; i < 2; i++)
                #pragma unroll
                for (int j = 0; j < 2; j++)
                    acc[i][j] = __builtin_amdgcn_mfma_f32_16x16x32_bf16(af[i], bfr[j], acc[i][j], 0, 0, 0);
        }
        __syncthreads();
    }
    #pragma unroll
    for (int i = 0; i < 2; i++) {
        #pragma unroll
        for (int j = 0; j < 2; j++) {
            int gn = col0 + wn * 32 + j * 16 + l16;
            int gm0 = row0 + wm * 32 + i * 16 + quad * 4;
            #pragma unroll
            for (int r = 0; r < 4; r++) {
                float v = acc[i][j][r];
                if (useBias) v += bias[gn];
                size_t o = (size_t)(gm0 + r) * N + gn;
                out[o] = v;
                if (useOutb) outb[o] = (bf16)v;
            }
        }
    }
}

// fp32 64x64 tile
__device__ __forceinline__ void gemm_f32_tile(
    const float* __restrict__ A, int lda, const float* __restrict__ W, int ldw,
    const float* __restrict__ bias, float* __restrict__ out, int ldout,
    int Nbound, int Kd, int kbase, int bx, int by,
    float (*AsF)[68], float (*WsF)[68], bool useBias, bool doSoft)
{
    const int tid = threadIdx.x;
    const int tx = tid & 15, ty = tid >> 4;
    const int tx4 = tx * 4, ty4 = ty * 4;
    const int row0 = by * 64, col0 = bx * 64;

    float acc[4][4] = {};
    for (int k0 = 0; k0 < Kd; k0 += 16) {
        #pragma unroll
        for (int i = 0; i < 4; i++) {
            int idx = tid + i * 256;
            int m = idx >> 4, kk = idx & 15;
            AsF[kk][m] = A[(size_t)(row0 + m) * lda + kbase + k0 + kk];
        }
        #pragma unroll
        for (int i = 0; i < 4; i++) {
            int idx = tid + i * 256;
            int nn = idx >> 4, kk = idx & 15;
            int gn = col0 + nn;
            WsF[kk][nn] = (gn < Nbound) ? W[(size_t)gn * ldw + kbase + k0 + kk] : 0.f;
        }
        __syncthreads();
        #pragma unroll
        for (int kk = 0; kk < 16; kk++) {
            float av[4], bv[4];
            #pragma unroll
            for (int i = 0; i < 4; i++) av[i] = AsF[kk][ty4 + i];
            #pragma unroll
            for (int j = 0; j < 4; j++) bv[j] = WsF[kk][tx4 + j];
            #pragma unroll
            for (int i = 0; i < 4; i++)
                #pragma unroll
                for (int j = 0; j < 4; j++)
                    acc[i][j] += av[i] * bv[j];
        }
        __syncthreads();
    }
    #pragma unroll
    for (int i = 0; i < 4; i++) {
        int gm = row0 + ty4 + i;
        #pragma unroll
        for (int j = 0; j < 4; j++) {
            int gn = col0 + tx4 + j;
            if (gn < Nbound) {
                float v = acc[i][j];
                if (useBias) v += bias[gn];
                if (doSoft) v = softplusf(v);
                out[(size_t)gm * ldout + gn] = v;
            }
        }
    }
}

__device__ __forceinline__ void rms_rows(const float* __restrict__ h, float* __restrict__ res,
                                         bf16* __restrict__ hnb, const float* __restrict__ w,
                                         int first, float* red, float* tot)
{
    const int tid = threadIdx.x;
    for (int t = blockIdx.x; t < LSEQ; t += gridDim.x) {
        float v[3]; float ss = 0.f;
        #pragma unroll
        for (int r = 0; r < 3; r++) {
            int j = tid + r * 256;
            float xv = h[(size_t)t * HDIM + j];
            if (!first) xv += res[(size_t)t * HDIM + j];
            v[r] = xv;
            res[(size_t)t * HDIM + j] = xv;
            ss += xv * xv;
        }
        #pragma unroll
        for (int m = 32; m >= 1; m >>= 1) ss += __shfl_down(ss, m);
        int wid = tid >> 6;
        if ((tid & 63) == 0) red[wid] = ss;
        __syncthreads();
        if (tid == 0) *tot = red[0] + red[1] + red[2] + red[3];
        __syncthreads();
        float scale = rsqrtf(*tot / (float)HDIM + 1e-5f);
        #pragma unroll
        for (int r = 0; r < 3; r++) {
            int j = tid + r * 256;
            hnb[(size_t)t * HDIM + j] = (bf16)(v[r] * scale * w[j]);
        }
        __syncthreads();
    }
}

__device__ __forceinline__ void conv_body(const float* __restrict__ xz, const float* __restrict__ cw,
                                          const float* __restrict__ cb, float* __restrict__ u)
{
    for (int idx = blockIdx.x * 256 + threadIdx.x; idx < LSEQ * EDIM; idx += gridDim.x * 256) {
        int t = idx / EDIM, e = idx - t * EDIM;
        float s = cb[e];
        #pragma unroll
        for (int k = 0; k < KCONV; k++) {
            int tt = t - (KCONV - 1) + k;
            if (tt >= 0) s += cw[e * KCONV + k] * xz[(size_t)tt * (2 * EDIM) + e];
        }
        u[(size_t)t * EDIM + e] = siluf(s);
    }
}

__device__ __forceinline__ void reduce_body(const float* __restrict__ part, float* __restrict__ dbc)
{
    for (int idx = blockIdx.x * 256 + threadIdx.x; idx < LSEQ * 80; idx += gridDim.x * 256) {
        float s = 0.f;
        #pragma unroll
        for (int k = 0; k < KSPLIT; k++) s += part[(size_t)k * (LSEQ * 80) + idx];
        dbc[idx] = s;
    }
}

__device__ __forceinline__ void scan1_block(int ex, int c,
    const float* __restrict__ dt, const float* __restrict__ u,
    const float* __restrict__ dbc, const float* __restrict__ a_log,
    float* __restrict__ chunkS, float* __restrict__ sumdt)
{
    const int e = ex * 256 + threadIdx.x;
    float A[16];
    #pragma unroll
    for (int q = 0; q < 4; q++) {
        float4 a4 = *(const float4*)(a_log + e * NDIM + q * 4);
        A[q*4+0] = -__expf(a4.x); A[q*4+1] = -__expf(a4.y);
        A[q*4+2] = -__expf(a4.z); A[q*4+3] = -__expf(a4.w);
    }
    float s[16] = {};
    float sd = 0.f;
    const int t0 = c * CHLEN;
    for (int t = t0; t < t0 + CHLEN; t++) {
        float dtv = dt[(size_t)t * EDIM + e];
        float uv  = u[(size_t)t * EDIM + e];
        float dtu = dtv * uv;
        sd += dtv;
        float4 B4[4];
        #pragma unroll
        for (int q = 0; q < 4; q++) B4[q] = *(const float4*)(dbc + (size_t)t * 80 + RDIM + q * 4);
        const float* B = (const float*)B4;
        #pragma unroll
        for (int n = 0; n < 16; n++) s[n] = s[n] * __expf(dtv * A[n]) + dtu * B[n];
    }
    float* cs = chunkS + ((size_t)c * EDIM + e) * NDIM;
    #pragma unroll
    for (int q = 0; q < 4; q++)
        *(float4*)(cs + q * 4) = make_float4(s[q*4+0], s[q*4+1], s[q*4+2], s[q*4+3]);
    sumdt[(size_t)c * EDIM + e] = sd;
}

__device__ __forceinline__ void scan2_body(const float* __restrict__ chunkS,
    const float* __restrict__ sumdt, const float* __restrict__ a_log,
    float* __restrict__ sInit)
{
    for (int gid = blockIdx.x * 256 + threadIdx.x; gid < EDIM * NDIM; gid += gridDim.x * 256) {
        int n = gid & 15, e = gid >> 4;
        const float Aen = -__expf(a_log[gid]);
        float s = 0.f;
        for (int c = 0; c < NCHUNK; c++) {
            sInit[((size_t)c * EDIM + e) * NDIM + n] = s;
            float P = __expf(Aen * sumdt[(size_t)c * EDIM + e]);
            s = s * P + chunkS[((size_t)c * EDIM + e) * NDIM + n];
        }
    }
}

__device__ __forceinline__ void scan3_block(int ex, int c,
    const float* __restrict__ dt, const float* __restrict__ u,
    const float* __restrict__ dbc, const float* __restrict__ xz,
    const float* __restrict__ a_log, const float* __restrict__ Dp,
    const float* __restrict__ sInit, bf16* __restrict__ yzb)
{
    const int e = ex * 256 + threadIdx.x;
    float A[16];
    #pragma unroll
    for (int q = 0; q < 4; q++) {
        float4 a4 = *(const float4*)(a_log + e * NDIM + q * 4);
        A[q*4+0] = -__expf(a4.x); A[q*4+1] = -__expf(a4.y);
        A[q*4+2] = -__expf(a4.z); A[q*4+3] = -__expf(a4.w);
    }
    const float dv = Dp[e];
    float s[16];
    const float* si = sInit + ((size_t)c * EDIM + e) * NDIM;
    #pragma unroll
    for (int q = 0; q < 4; q++) {
        float4 s4 = *(const float4*)(si + q * 4);
        s[q*4+0] = s4.x; s[q*4+1] = s4.y; s[q*4+2] = s4.z; s[q*4+3] = s4.w;
    }
    const int t0 = c * CHLEN;
    for (int t = t0; t < t0 + CHLEN; t++) {
        float dtv = dt[(size_t)t * EDIM + e];
        float uv  = u[(size_t)t * EDIM + e];
        float zv  = xz[(size_t)t * (2 * EDIM) + EDIM + e];
        float dtu = dtv * uv;
        float4 B4[4], C4[4];
        #pragma unroll
        for (int q = 0; q < 4; q++) {
            B4[q] = *(const float4*)(dbc + (size_t)t * 80 + RDIM + q * 4);
            C4[q] = *(const float4*)(dbc + (size_t)t * 80 + RDIM + NDIM + q * 4);
        }
        const float* B = (const float*)B4;
        const float* C = (const float*)C4;
        float y = 0.f;
        #pragma unroll
        for (int n = 0; n < 16; n++) {
            s[n] = s[n] * __expf(dtv * A[n]) + dtu * B[n];
            y += s[n] * C[n];
        }
        y += uv * dv;
        yzb[(size_t)t * EDIM + e] = (bf16)(y * siluf(zv));
    }
}

// ================= cooperative mega kernel (grid-size agnostic) =================
__global__ __launch_bounds__(256) void mamba_mega(MegaArgs a)
{
    cg::grid_group grid = cg::this_grid();
    const int bid = blockIdx.x, tid = threadIdx.x;
    const int GN = gridDim.x;

    __shared__ __align__(16) short AsB[64][72];
    __shared__ __align__(16) short WsB[64][72];
    __shared__ float AsF[16][68];
    __shared__ float WsF[16][68];
    __shared__ float rms_red[4];
    __shared__ float rms_tot;

    f2b_seg(a.x, a.xb, LSEQ * SDIM);
    f2b_seg(a.emb_w, a.emb_wb, HDIM * SDIM);
    f2b_seg(a.head_w, a.head_wb, SDIM * HDIM);
    f2b_seg(a.in_proj, a.in_wb, NLAYER * 2 * EDIM * HDIM);
    f2b_seg(a.out_proj, a.out_wb, NLAYER * HDIM * EDIM);
    grid.sync();

    for (int t = bid; t < 192; t += GN)
        gemm_tile(a.xb, SDIM, a.emb_wb, SDIM, a.emb_b, a.h, nullptr,
                  HDIM, SDIM, t % 12, t / 12, AsB, WsB, true, false);
    grid.sync();

    for (int l = 0; l < NLAYER; l++) {
        const bf16*  inw  = a.in_wb  + (size_t)l * 2 * EDIM * HDIM;
        const bf16*  outw = a.out_wb + (size_t)l * HDIM * EDIM;
        const float* cw   = a.conv_w + (size_t)l * EDIM * KCONV;
        const float* cb   = a.conv_b + (size_t)l * EDIM;
        const float* xw   = a.x_proj + (size_t)l * 80 * EDIM;
        const float* dtw  = a.dt_w   + (size_t)l * EDIM * RDIM;
        const float* dtbb = a.dt_b   + (size_t)l * EDIM;
        const float* al   = a.A_log  + (size_t)l * EDIM * NDIM;
        const float* Dpl  = a.Dp     + (size_t)l * EDIM;

        rms_rows(a.h, a.res, a.hnb, a.norm_w + (size_t)l * HDIM, l == 0, rms_red, &rms_tot);
        grid.sync();

        for (int t = bid; t < 768; t += GN)
            gemm_tile(a.hnb, HDIM, inw, HDIM, nullptr, a.xz, nullptr,
                      2 * EDIM, HDIM, t % 48, t / 48, AsB, WsB, false, false);
        grid.sync();

        conv_body(a.xz, cw, cb, a.u);
        grid.sync();

        for (int t = bid; t < 256; t += GN)
            gemm_f32_tile(a.u, EDIM, xw, EDIM, nullptr,
                          a.part + (size_t)(t / 32) * (LSEQ * 80), 80,
                          80, KCH, (t / 32) * KCH, t % 2, (t / 2) % 16,
                          AsF, WsF, false, false);
        grid.sync();

        reduce_body(a.part, a.dbc);
        grid.sync();

        for (int t = bid; t < 384; t += GN)
            gemm_f32_tile(a.dbc, 80, dtw, RDIM, dtbb, a.dtb, EDIM,
                          EDIM, RDIM, 0, t % 24, t / 24, AsF, WsF, true, true);
        grid.sync();

        for (int b = bid; b < 6 * NCHUNK; b += GN)
            scan1_block(b % 6, b / 6, a.dtb, a.u, a.dbc, al, a.chunkS, a.sumdt);
        grid.sync();

        scan2_body(a.chunkS, a.sumdt, al, a.sInit);
        grid.sync();

        for (int b = bid; b < 6 * NCHUNK; b += GN)
            scan3_block(b % 6, b / 6, a.dtb, a.u, a.dbc, a.xz, al, Dpl, a.sInit, a.yzb);
        grid.sync();

        bool last = (l == NLAYER - 1);
        for (int t = bid; t < 192; t += GN)
            gemm_tile(a.yzb, EDIM, outw, EDIM, nullptr, a.h, a.hb,
                      HDIM, EDIM, t % 12, t / 12, AsB, WsB, false, last);
        grid.sync();
    }

    for (int t = bid; t < 64; t += GN)
        gemm_tile(a.hb, HDIM, a.head_wb, HDIM, a.head_b, a.out, nullptr,
                  SDIM, HDIM, t % 4, t / 4, AsB, WsB, true, false);
}

// ================= fallback wrappers (multi-kernel chain) =================
__global__ __launch_bounds__(256) void k_f2b(const float* in, bf16* out, int n) { f2b_seg(in, out, n); }

__global__ __launch_bounds__(256) void k_gemm(const bf16* A, int lda, const bf16* W, int ldw,
                                              const float* bias, float* out, bf16* outb,
                                              int N, int Kd, int useBias, int useOutb)
{
    __shared__ __align__(16) short As[64][72];
    __shared__ __align__(16) short Ws[64][72];
    gemm_tile(A, lda, W, ldw, bias, out, outb, N, Kd, blockIdx.x, blockIdx.y, As, Ws,
              useBias != 0, useOutb != 0);
}

__global__ __launch_bounds__(256) void k_xproj(const float* u, const float* xw, float* part)
{
    __shared__ float AsF[16][68];
    __shared__ float WsF[16][68];
    gemm_f32_tile(u, EDIM, xw, EDIM, nullptr, part + (size_t)blockIdx.z * (LSEQ * 80), 80,
                  80, KCH, blockIdx.z * KCH, blockIdx.x, blockIdx.y, AsF, WsF, false, false);
}

__global__ __launch_bounds__(256) void k_dt(const float* dbc, const float* dtw,
                                            const float* dtbb, float* out)
{
    __shared__ float AsF[16][68];
    __shared__ float WsF[16][68];
    gemm_f32_tile(dbc, 80, dtw, RDIM, dtbb, out, EDIM, EDIM, RDIM, 0,
                  blockIdx.x, blockIdx.y, AsF, WsF, true, true);
}

__global__ __launch_bounds__(256) void k_rms(const float* h, float* res, bf16* hnb,
                                             const float* w, int first)
{
    __shared__ float red[4];
    __shared__ float tot;
    rms_rows(h, res, hnb, w, first, red, &tot);
}

__global__ __launch_bounds__(256) void k_conv(const float* xz, const float* cw,
                                              const float* cb, float* u) { conv_body(xz, cw, cb, u); }

__global__ __launch_bounds__(256) void k_reduce(const float* part, float* dbc) { reduce_body(part, dbc); }

__global__ __launch_bounds__(256) void k_scan1(const float* dt, const float* u, const float* dbc,
                                               const float* al, float* chunkS, float* sumdt)
{
    scan1_block(blockIdx.x % 6, blockIdx.x / 6, dt, u, dbc, al, chunkS, sumdt);
}

__global__ __launch_bounds__(256) void k_scan2(const float* chunkS, const float* sumdt,
                                               const float* al, float* sInit)
{
    scan2_body(chunkS, sumdt, al, sInit);
}

__global__ __launch_bounds__(256) void k_scan3(const float* dt, const float* u, const float* dbc,
                                               const float* xz, const float* al, const float* Dp,
                                               const float* sInit, bf16* yzb)
{
    scan3_block(blockIdx.x % 6, blockIdx.x / 6, dt, u, dbc, xz, al, Dp, sInit, yzb);
}

extern "C" void kernel_launch(void* const* d_in, const int* in_sizes, int n_in,
                              void* d_out, int out_size, void* d_ws, size_t ws_size,
                              hipStream_t stream)
{
    MegaArgs a;
    a.x        = (const float*)d_in[0];
    a.emb_w    = (const float*)d_in[1];
    a.emb_b    = (const float*)d_in[2];
    a.norm_w   = (const float*)d_in[3];
    a.in_proj  = (const float*)d_in[4];
    a.conv_w   = (const float*)d_in[5];
    a.conv_b   = (const float*)d_in[6];
    a.x_proj   = (const float*)d_in[7];
    a.dt_w     = (const float*)d_in[8];
    a.dt_b     = (const float*)d_in[9];
    a.A_log    = (const float*)d_in[10];
    a.Dp       = (const float*)d_in[11];
    a.out_proj = (const float*)d_in[12];
    a.head_w   = (const float*)d_in[13];
    a.head_b   = (const float*)d_in[14];
    a.out      = (float*)d_out;

    float* ws = (float*)d_ws;
    size_t off = 0;
    a.h      = ws + off; off += (size_t)LSEQ * HDIM;
    a.res    = ws + off; off += (size_t)LSEQ * HDIM;
    a.xz     = ws + off; off += (size_t)LSEQ * 2 * EDIM;
    a.u      = ws + off; off += (size_t)LSEQ * EDIM;
    a.dbc    = ws + off; off += (size_t)LSEQ * 80;
    a.part   = ws + off; off += (size_t)KSPLIT * LSEQ * 80;
    a.dtb    = ws + off; off += (size_t)LSEQ * EDIM;
    a.chunkS = ws + off; off += (size_t)NCHUNK * EDIM * NDIM;
    a.sumdt  = ws + off; off += (size_t)NCHUNK * EDIM;
    a.sInit  = ws + off; off += (size_t)NCHUNK * EDIM * NDIM;
    a.hnb     = (bf16*)(ws + off); off += (size_t)LSEQ * HDIM / 2;
    a.yzb     = (bf16*)(ws + off); off += (size_t)LSEQ * EDIM / 2;
    a.hb      = (bf16*)(ws + off); off += (size_t)LSEQ * HDIM / 2;
    a.xb      = (bf16*)(ws + off); off += (size_t)LSEQ * SDIM / 2;
    a.emb_wb  = (bf16*)(ws + off); off += (size_t)HDIM * SDIM / 2;
    a.head_wb = (bf16*)(ws + off); off += (size_t)SDIM * HDIM / 2;
    a.in_wb   = (bf16*)(ws + off); off += (size_t)NLAYER * 2 * EDIM * HDIM / 2;
    a.out_wb  = (bf16*)(ws + off); off += (size_t)NLAYER * HDIM * EDIM / 2;

    // size the cooperative grid with the runtime's own occupancy calculator:
    // use FULL capacity (nb blocks/CU x 256 CUs), capped at 1024 (4/CU).
    int dev = 0;
    (void)hipGetDevice(&dev);
    int ncu = 0;
    (void)hipDeviceGetAttribute(&ncu, hipDeviceAttributeMultiprocessorCount, dev);
    int nb = 0;
    hipError_t occ = hipOccupancyMaxActiveBlocksPerMultiprocessor(
        &nb, (const void*)mamba_mega, 256, 0);

    int gridN = 0;
    if (occ == hipSuccess && nb > 0 && ncu > 0) {
        long long cap = (long long)nb * (long long)ncu;
        gridN = (cap > 1024) ? 1024 : (int)cap;
    }

    hipError_t err = hipErrorUnknown;
    if (gridN >= 64) {
        void* params[] = { &a };
        err = hipLaunchCooperativeKernel((const void*)mamba_mega, dim3(gridN), dim3(256),
                                         params, 0, stream);
    }
    if (err == hipSuccess) return;

    // ---------- fallback: proven multi-kernel chain ----------
    k_f2b<<<256, 256, 0, stream>>>(a.x, a.xb, LSEQ * SDIM);
    k_f2b<<<256, 256, 0, stream>>>(a.emb_w, a.emb_wb, HDIM * SDIM);
    k_f2b<<<256, 256, 0, stream>>>(a.head_w, a.head_wb, SDIM * HDIM);
    k_f2b<<<512, 256, 0, stream>>>(a.in_proj, a.in_wb, NLAYER * 2 * EDIM * HDIM);
    k_f2b<<<512, 256, 0, stream>>>(a.out_proj, a.out_wb, NLAYER * HDIM * EDIM);

    k_gemm<<<dim3(12, 16), 256, 0, stream>>>(a.xb, SDIM, a.emb_wb, SDIM, a.emb_b,
                                             a.h, nullptr, HDIM, SDIM, 1, 0);
    for (int l = 0; l < NLAYER; l++) {
        const bf16*  inw  = a.in_wb  + (size_t)l * 2 * EDIM * HDIM;
        const bf16*  outw = a.out_wb + (size_t)l * HDIM * EDIM;
        const float* cw   = a.conv_w + (size_t)l * EDIM * KCONV;
        const float* cb   = a.conv_b + (size_t)l * EDIM;
        const float* xw   = a.x_proj + (size_t)l * 80 * EDIM;
        const float* dtw  = a.dt_w   + (size_t)l * EDIM * RDIM;
        const float* dtbb = a.dt_b   + (size_t)l * EDIM;
        const float* al   = a.A_log  + (size_t)l * EDIM * NDIM;
        const float* Dpl  = a.Dp     + (size_t)l * EDIM;

        k_rms<<<LSEQ, 256, 0, stream>>>(a.h, a.res, a.hnb, a.norm_w + (size_t)l * HDIM, l == 0);
        k_gemm<<<dim3(48, 16), 256, 0, stream>>>(a.hnb, HDIM, inw, HDIM, nullptr,
                                                 a.xz, nullptr, 2 * EDIM, HDIM, 0, 0);
        k_conv<<<2048, 256, 0, stream>>>(a.xz, cw, cb, a.u);
        k_xproj<<<dim3(2, 16, KSPLIT), 256, 0, stream>>>(a.u, xw, a.part);
        k_reduce<<<320, 256, 0, stream>>>(a.part, a.dbc);
        k_dt<<<dim3(24, 16), 256, 0, stream>>>(a.dbc, dtw, dtbb, a.dtb);
        k_scan1<<<6 * NCHUNK, 256, 0, stream>>>(a.dtb, a.u, a.dbc, al, a.chunkS, a.sumdt);
        k_scan2<<<96, 256, 0, stream>>>(a.chunkS, a.sumdt, al, a.sInit);
        k_scan3<<<6 * NCHUNK, 256, 0, stream>>>(a.dtb, a.u, a.dbc, a.xz, al, Dpl, a.sInit, a.yzb);
        k_gemm<<<dim3(12, 16), 256, 0, stream>>>(a.yzb, EDIM, outw, EDIM, nullptr,
                                                 a.h, a.hb, HDIM, EDIM, 0, (l == NLAYER - 1) ? 1 : 0);
    }
    k_gemm<<<dim3(4, 16), 256, 0, stream>>>(a.hb, HDIM, a.head_wb, HDIM, a.head_b,
                                            a.out, nullptr, SDIM, HDIM, 1, 0);
}

// Round 10
// 432.549 us; speedup vs baseline: 2.6254x; 2.6254x over previous
//
#include <hip/hip_runtime.h>
#include <hip/hip_bf16.h>
#include <math.h>

// Problem dims
#define SDIM 256
#define HDIM 768
#define EDIM 1536
#define NDIM 16
#define KCONV 4
#define RDIM 48
#define NLAYER 2
#define LSEQ 1024

#define NCHUNK 64
#define CHLEN (LSEQ / NCHUNK)   // 16
#define KSPLIT 8
#define KCH (EDIM / KSPLIT)     // 192

typedef __hip_bfloat16 bf16;
typedef __attribute__((ext_vector_type(8))) short short8;
typedef __attribute__((ext_vector_type(4))) float f32x4;

__device__ __forceinline__ float softplusf(float x) {
    return (x > 20.f) ? x : log1pf(expf(x));
}
__device__ __forceinline__ float siluf(float x) {
    return x / (1.f + expf(-x));
}

// ---------------- combined fp32 -> bf16 conversion: 5 segments, one launch ----------------
struct F2BSegs {
    const float* src[5];
    bf16*        dst[5];
    int          n[5];      // element counts (each % 4 == 0)
};

__global__ __launch_bounds__(256) void f2b_all(F2BSegs segs)
{
    for (int s = 0; s < 5; s++) {
        const float* __restrict__ in = segs.src[s];
        bf16* __restrict__ out = segs.dst[s];
        const int n = segs.n[s];
        for (int i = (blockIdx.x * 256 + threadIdx.x) * 4; i < n; i += gridDim.x * 256 * 4) {
            float4 v = *(const float4*)(in + i);
            out[i + 0] = (bf16)v.x; out[i + 1] = (bf16)v.y;
            out[i + 2] = (bf16)v.z; out[i + 3] = (bf16)v.w;
        }
    }
}

// ---------------- MFMA bf16 GEMM 64x64 tile ----------------
__global__ __launch_bounds__(256) void k_gemm(const bf16* __restrict__ A, int lda,
                                              const bf16* __restrict__ W, int ldw,
                                              const float* __restrict__ bias,
                                              float* __restrict__ out, bf16* __restrict__ outb,
                                              int N, int Kd, int useBias, int useOutb)
{
    __shared__ __align__(16) short As[64][72];   // +8 pad: 2-way bank alias only (free, m136)
    __shared__ __align__(16) short Ws[64][72];

    const int tid  = threadIdx.x;
    const int lane = tid & 63, wid = tid >> 6;
    const int wm = wid >> 1, wn = wid & 1;
    const int row0 = blockIdx.y * 64, col0 = blockIdx.x * 64;
    const int quad = lane >> 4, l16 = lane & 15;

    f32x4 acc[2][2] = {};
    for (int k0 = 0; k0 < Kd; k0 += 64) {
        #pragma unroll
        for (int i = 0; i < 2; i++) {
            int id = tid + i * 256;
            int r = id >> 3, g = id & 7;
            *(uint4*)&As[r][g * 8] = *(const uint4*)(A + (size_t)(row0 + r) * lda + k0 + g * 8);
            *(uint4*)&Ws[r][g * 8] = *(const uint4*)(W + (size_t)(col0 + r) * ldw + k0 + g * 8);
        }
        __syncthreads();
        #pragma unroll
        for (int ks = 0; ks < 64; ks += 32) {
            short8 af[2], bfr[2];
            #pragma unroll
            for (int i = 0; i < 2; i++) af[i] = *(const short8*)&As[wm * 32 + i * 16 + l16][ks + quad * 8];
            #pragma unroll
            for (int j = 0; j < 2; j++) bfr[j] = *(const short8*)&Ws[wn * 32 + j * 16 + l16][ks + quad * 8];
            #pragma unroll
            for (int i = 0; i < 2; i++)
                #pragma unroll
                for (int j = 0; j < 2; j++)
                    acc[i][j] = __builtin_amdgcn_mfma_f32_16x16x32_bf16(af[i], bfr[j], acc[i][j], 0, 0, 0);
        }
        __syncthreads();
    }
    // C layout: col = lane&15, row = quad*4 + reg
    #pragma unroll
    for (int i = 0; i < 2; i++) {
        #pragma unroll
        for (int j = 0; j < 2; j++) {
            int gn = col0 + wn * 32 + j * 16 + l16;
            int gm0 = row0 + wm * 32 + i * 16 + quad * 4;
            #pragma unroll
            for (int r = 0; r < 4; r++) {
                float v = acc[i][j][r];
                if (useBias) v += bias[gn];
                size_t o = (size_t)(gm0 + r) * N + gn;
                out[o] = v;
                if (useOutb) outb[o] = (bf16)v;
            }
        }
    }
}

// ---------------- fp32 64x64 tile GEMM helper ----------------
__device__ __forceinline__ void gemm_f32_tile(
    const float* __restrict__ A, int lda, const float* __restrict__ W, int ldw,
    const float* __restrict__ bias, float* __restrict__ out, int ldout,
    int Nbound, int Kd, int kbase, int bx, int by,
    float (*AsF)[68], float (*WsF)[68], bool useBias, bool doSoft)
{
    const int tid = threadIdx.x;
    const int tx = tid & 15, ty = tid >> 4;
    const int tx4 = tx * 4, ty4 = ty * 4;
    const int row0 = by * 64, col0 = bx * 64;

    float acc[4][4] = {};
    for (int k0 = 0; k0 < Kd; k0 += 16) {
        #pragma unroll
        for (int i = 0; i < 4; i++) {
            int idx = tid + i * 256;
            int m = idx >> 4, kk = idx & 15;
            AsF[kk][m] = A[(size_t)(row0 + m) * lda + kbase + k0 + kk];
        }
        #pragma unroll
        for (int i = 0; i < 4; i++) {
            int idx = tid + i * 256;
            int nn = idx >> 4, kk = idx & 15;
            int gn = col0 + nn;
            WsF[kk][nn] = (gn < Nbound) ? W[(size_t)gn * ldw + kbase + k0 + kk] : 0.f;
        }
        __syncthreads();
        #pragma unroll
        for (int kk = 0; kk < 16; kk++) {
            float av[4], bv[4];
            #pragma unroll
            for (int i = 0; i < 4; i++) av[i] = AsF[kk][ty4 + i];
            #pragma unroll
            for (int j = 0; j < 4; j++) bv[j] = WsF[kk][tx4 + j];
            #pragma unroll
            for (int i = 0; i < 4; i++)
                #pragma unroll
                for (int j = 0; j < 4; j++)
                    acc[i][j] += av[i] * bv[j];
        }
        __syncthreads();
    }
    #pragma unroll
    for (int i = 0; i < 4; i++) {
        int gm = row0 + ty4 + i;
        #pragma unroll
        for (int j = 0; j < 4; j++) {
            int gn = col0 + tx4 + j;
            if (gn < Nbound) {
                float v = acc[i][j];
                if (useBias) v += bias[gn];
                if (doSoft) v = softplusf(v);
                out[(size_t)gm * ldout + gn] = v;
            }
        }
    }
}

__global__ __launch_bounds__(256) void k_xproj(const float* __restrict__ u,
                                               const float* __restrict__ xw,
                                               float* __restrict__ part)
{
    __shared__ float AsF[16][68];
    __shared__ float WsF[16][68];
    gemm_f32_tile(u, EDIM, xw, EDIM, nullptr, part + (size_t)blockIdx.z * (LSEQ * 80), 80,
                  80, KCH, blockIdx.z * KCH, blockIdx.x, blockIdx.y, AsF, WsF, false, false);
}

__global__ __launch_bounds__(256) void k_dt(const float* __restrict__ dbc,
                                            const float* __restrict__ dtw,
                                            const float* __restrict__ dtbb,
                                            float* __restrict__ out)
{
    __shared__ float AsF[16][68];
    __shared__ float WsF[16][68];
    gemm_f32_tile(dbc, 80, dtw, RDIM, dtbb, out, EDIM, EDIM, RDIM, 0,
                  blockIdx.x, blockIdx.y, AsF, WsF, true, true);
}

// ---------------- residual + rmsnorm ----------------
__global__ __launch_bounds__(256) void k_rms(const float* __restrict__ h, float* __restrict__ res,
                                             bf16* __restrict__ hnb, const float* __restrict__ w,
                                             int first)
{
    __shared__ float red[4];
    __shared__ float tot;
    const int tid = threadIdx.x;
    const int t = blockIdx.x;
    float v[3]; float ss = 0.f;
    #pragma unroll
    for (int r = 0; r < 3; r++) {
        int j = tid + r * 256;
        float xv = h[(size_t)t * HDIM + j];
        if (!first) xv += res[(size_t)t * HDIM + j];
        v[r] = xv;
        res[(size_t)t * HDIM + j] = xv;
        ss += xv * xv;
    }
    #pragma unroll
    for (int m = 32; m >= 1; m >>= 1) ss += __shfl_down(ss, m);
    int wid = tid >> 6;
    if ((tid & 63) == 0) red[wid] = ss;
    __syncthreads();
    if (tid == 0) tot = red[0] + red[1] + red[2] + red[3];
    __syncthreads();
    float scale = rsqrtf(tot / (float)HDIM + 1e-5f);
    #pragma unroll
    for (int r = 0; r < 3; r++) {
        int j = tid + r * 256;
        hnb[(size_t)t * HDIM + j] = (bf16)(v[r] * scale * w[j]);
    }
}

// ---------------- conv + silu ----------------
__global__ __launch_bounds__(256) void k_conv(const float* __restrict__ xz,
                                              const float* __restrict__ cw,
                                              const float* __restrict__ cb,
                                              float* __restrict__ u)
{
    for (int idx = blockIdx.x * 256 + threadIdx.x; idx < LSEQ * EDIM; idx += gridDim.x * 256) {
        int t = idx / EDIM, e = idx - t * EDIM;
        float s = cb[e];
        #pragma unroll
        for (int k = 0; k < KCONV; k++) {
            int tt = t - (KCONV - 1) + k;
            if (tt >= 0) s += cw[e * KCONV + k] * xz[(size_t)tt * (2 * EDIM) + e];
        }
        u[(size_t)t * EDIM + e] = siluf(s);
    }
}

// ---------------- reduce split-K partials ----------------
__global__ __launch_bounds__(256) void k_reduce(const float* __restrict__ part,
                                                float* __restrict__ dbc)
{
    for (int idx = blockIdx.x * 256 + threadIdx.x; idx < LSEQ * 80; idx += gridDim.x * 256) {
        float s = 0.f;
        #pragma unroll
        for (int k = 0; k < KSPLIT; k++) s += part[(size_t)k * (LSEQ * 80) + idx];
        dbc[idx] = s;
    }
}

// ---------------- selective scan (thread per e, 16 states in regs) ----------------
__global__ __launch_bounds__(256) void k_scan1(const float* __restrict__ dt,
                                               const float* __restrict__ u,
                                               const float* __restrict__ dbc,
                                               const float* __restrict__ a_log,
                                               float* __restrict__ chunkS,
                                               float* __restrict__ sumdt)
{
    const int ex = blockIdx.x % 6, c = blockIdx.x / 6;
    const int e = ex * 256 + threadIdx.x;
    float A[16];
    #pragma unroll
    for (int q = 0; q < 4; q++) {
        float4 a4 = *(const float4*)(a_log + e * NDIM + q * 4);
        A[q*4+0] = -__expf(a4.x); A[q*4+1] = -__expf(a4.y);
        A[q*4+2] = -__expf(a4.z); A[q*4+3] = -__expf(a4.w);
    }
    float s[16] = {};
    float sd = 0.f;
    const int t0 = c * CHLEN;
    for (int t = t0; t < t0 + CHLEN; t++) {
        float dtv = dt[(size_t)t * EDIM + e];
        float uv  = u[(size_t)t * EDIM + e];
        float dtu = dtv * uv;
        sd += dtv;
        float4 B4[4];
        #pragma unroll
        for (int q = 0; q < 4; q++) B4[q] = *(const float4*)(dbc + (size_t)t * 80 + RDIM + q * 4);
        const float* B = (const float*)B4;
        #pragma unroll
        for (int n = 0; n < 16; n++) s[n] = s[n] * __expf(dtv * A[n]) + dtu * B[n];
    }
    float* cs = chunkS + ((size_t)c * EDIM + e) * NDIM;
    #pragma unroll
    for (int q = 0; q < 4; q++)
        *(float4*)(cs + q * 4) = make_float4(s[q*4+0], s[q*4+1], s[q*4+2], s[q*4+3]);
    sumdt[(size_t)c * EDIM + e] = sd;
}

__global__ __launch_bounds__(256) void k_scan2(const float* __restrict__ chunkS,
                                               const float* __restrict__ sumdt,
                                               const float* __restrict__ a_log,
                                               float* __restrict__ sInit)
{
    int gid = blockIdx.x * 256 + threadIdx.x;
    if (gid >= EDIM * NDIM) return;
    int n = gid & 15, e = gid >> 4;
    const float Aen = -__expf(a_log[gid]);
    float s = 0.f;
    for (int c = 0; c < NCHUNK; c++) {
        sInit[((size_t)c * EDIM + e) * NDIM + n] = s;
        float P = __expf(Aen * sumdt[(size_t)c * EDIM + e]);
        s = s * P + chunkS[((size_t)c * EDIM + e) * NDIM + n];
    }
}

__global__ __launch_bounds__(256) void k_scan3(const float* __restrict__ dt,
                                               const float* __restrict__ u,
                                               const float* __restrict__ dbc,
                                               const float* __restrict__ xz,
                                               const float* __restrict__ a_log,
                                               const float* __restrict__ Dp,
                                               const float* __restrict__ sInit,
                                               bf16* __restrict__ yzb)
{
    const int ex = blockIdx.x % 6, c = blockIdx.x / 6;
    const int e = ex * 256 + threadIdx.x;
    float A[16];
    #pragma unroll
    for (int q = 0; q < 4; q++) {
        float4 a4 = *(const float4*)(a_log + e * NDIM + q * 4);
        A[q*4+0] = -__expf(a4.x); A[q*4+1] = -__expf(a4.y);
        A[q*4+2] = -__expf(a4.z); A[q*4+3] = -__expf(a4.w);
    }
    const float dv = Dp[e];
    float s[16];
    const float* si = sInit + ((size_t)c * EDIM + e) * NDIM;
    #pragma unroll
    for (int q = 0; q < 4; q++) {
        float4 s4 = *(const float4*)(si + q * 4);
        s[q*4+0] = s4.x; s[q*4+1] = s4.y; s[q*4+2] = s4.z; s[q*4+3] = s4.w;
    }
    const int t0 = c * CHLEN;
    for (int t = t0; t < t0 + CHLEN; t++) {
        float dtv = dt[(size_t)t * EDIM + e];
        float uv  = u[(size_t)t * EDIM + e];
        float zv  = xz[(size_t)t * (2 * EDIM) + EDIM + e];
        float dtu = dtv * uv;
        float4 B4[4], C4[4];
        #pragma unroll
        for (int q = 0; q < 4; q++) {
            B4[q] = *(const float4*)(dbc + (size_t)t * 80 + RDIM + q * 4);
            C4[q] = *(const float4*)(dbc + (size_t)t * 80 + RDIM + NDIM + q * 4);
        }
        const float* B = (const float*)B4;
        const float* C = (const float*)C4;
        float y = 0.f;
        #pragma unroll
        for (int n = 0; n < 16; n++) {
            s[n] = s[n] * __expf(dtv * A[n]) + dtu * B[n];
            y += s[n] * C[n];
        }
        y += uv * dv;
        yzb[(size_t)t * EDIM + e] = (bf16)(y * siluf(zv));
    }
}

extern "C" void kernel_launch(void* const* d_in, const int* in_sizes, int n_in,
                              void* d_out, int out_size, void* d_ws, size_t ws_size,
                              hipStream_t stream)
{
    const float* x        = (const float*)d_in[0];
    const float* emb_w    = (const float*)d_in[1];
    const float* emb_b    = (const float*)d_in[2];
    const float* norm_w   = (const float*)d_in[3];
    const float* in_proj  = (const float*)d_in[4];
    const float* conv_w   = (const float*)d_in[5];
    const float* conv_b   = (const float*)d_in[6];
    const float* x_proj   = (const float*)d_in[7];
    const float* dt_w     = (const float*)d_in[8];
    const float* dt_b     = (const float*)d_in[9];
    const float* A_log    = (const float*)d_in[10];
    const float* Dp       = (const float*)d_in[11];
    const float* out_proj = (const float*)d_in[12];
    const float* head_w   = (const float*)d_in[13];
    const float* head_b   = (const float*)d_in[14];
    float* out = (float*)d_out;

    float* ws = (float*)d_ws;
    size_t off = 0;
    float* h      = ws + off; off += (size_t)LSEQ * HDIM;
    float* res    = ws + off; off += (size_t)LSEQ * HDIM;
    float* xz     = ws + off; off += (size_t)LSEQ * 2 * EDIM;
    float* u      = ws + off; off += (size_t)LSEQ * EDIM;
    float* dbc    = ws + off; off += (size_t)LSEQ * 80;
    float* part   = ws + off; off += (size_t)KSPLIT * LSEQ * 80;
    float* dtb    = ws + off; off += (size_t)LSEQ * EDIM;
    float* chunkS = ws + off; off += (size_t)NCHUNK * EDIM * NDIM;
    float* sumdt  = ws + off; off += (size_t)NCHUNK * EDIM;
    float* sInit  = ws + off; off += (size_t)NCHUNK * EDIM * NDIM;
    bf16* hnb     = (bf16*)(ws + off); off += (size_t)LSEQ * HDIM / 2;
    bf16* yzb     = (bf16*)(ws + off); off += (size_t)LSEQ * EDIM / 2;
    bf16* hb      = (bf16*)(ws + off); off += (size_t)LSEQ * HDIM / 2;
    bf16* xb      = (bf16*)(ws + off); off += (size_t)LSEQ * SDIM / 2;
    bf16* emb_wb  = (bf16*)(ws + off); off += (size_t)HDIM * SDIM / 2;
    bf16* head_wb = (bf16*)(ws + off); off += (size_t)SDIM * HDIM / 2;
    bf16* in_wb   = (bf16*)(ws + off); off += (size_t)NLAYER * 2 * EDIM * HDIM / 2;
    bf16* out_wb  = (bf16*)(ws + off); off += (size_t)NLAYER * HDIM * EDIM / 2;

    // one launch: all fp32->bf16 conversions (x + all weights, both layers)
    F2BSegs segs;
    segs.src[0] = x;        segs.dst[0] = xb;      segs.n[0] = LSEQ * SDIM;
    segs.src[1] = emb_w;    segs.dst[1] = emb_wb;  segs.n[1] = HDIM * SDIM;
    segs.src[2] = head_w;   segs.dst[2] = head_wb; segs.n[2] = SDIM * HDIM;
    segs.src[3] = in_proj;  segs.dst[3] = in_wb;   segs.n[3] = NLAYER * 2 * EDIM * HDIM;
    segs.src[4] = out_proj; segs.dst[4] = out_wb;  segs.n[4] = NLAYER * HDIM * EDIM;
    f2b_all<<<1024, 256, 0, stream>>>(segs);

    // embed: h = x @ emb_w^T + emb_b  (N=768, K=256)
    k_gemm<<<dim3(12, 16), 256, 0, stream>>>(xb, SDIM, emb_wb, SDIM, emb_b,
                                             h, nullptr, HDIM, SDIM, 1, 0);

    for (int l = 0; l < NLAYER; l++) {
        const bf16*  inw  = in_wb  + (size_t)l * 2 * EDIM * HDIM;
        const bf16*  outw = out_wb + (size_t)l * HDIM * EDIM;
        const float* cw   = conv_w + (size_t)l * EDIM * KCONV;
        const float* cb   = conv_b + (size_t)l * EDIM;
        const float* xw   = x_proj + (size_t)l * 80 * EDIM;
        const float* dtw  = dt_w   + (size_t)l * EDIM * RDIM;
        const float* dtbb = dt_b   + (size_t)l * EDIM;
        const float* al   = A_log  + (size_t)l * EDIM * NDIM;
        const float* Dpl  = Dp     + (size_t)l * EDIM;

        k_rms<<<LSEQ, 256, 0, stream>>>(h, res, hnb, norm_w + (size_t)l * HDIM, l == 0);
        k_gemm<<<dim3(48, 16), 256, 0, stream>>>(hnb, HDIM, inw, HDIM, nullptr,
                                                 xz, nullptr, 2 * EDIM, HDIM, 0, 0);
        k_conv<<<2048, 256, 0, stream>>>(xz, cw, cb, u);
        k_xproj<<<dim3(2, 16, KSPLIT), 256, 0, stream>>>(u, xw, part);
        k_reduce<<<320, 256, 0, stream>>>(part, dbc);
        k_dt<<<dim3(24, 16), 256, 0, stream>>>(dbc, dtw, dtbb, dtb);
        k_scan1<<<6 * NCHUNK, 256, 0, stream>>>(dtb, u, dbc, al, chunkS, sumdt);
        k_scan2<<<96, 256, 0, stream>>>(chunkS, sumdt, al, sInit);
        k_scan3<<<6 * NCHUNK, 256, 0, stream>>>(dtb, u, dbc, xz, al, Dpl, sInit, yzb);
        k_gemm<<<dim3(12, 16), 256, 0, stream>>>(yzb, EDIM, outw, EDIM, nullptr,
                                                 h, hb, HDIM, EDIM, 0, (l == NLAYER - 1) ? 1 : 0);
    }

    // head: out = h @ head_w^T + head_b  (N=256, K=768)
    k_gemm<<<dim3(4, 16), 256, 0, stream>>>(hb, HDIM, head_wb, HDIM, head_b,
                                            out, nullptr, SDIM, HDIM, 1, 0);
}